// Round 1
// 364.952 us; speedup vs baseline: 1.1208x; 1.1208x over previous
//
#include <hip/hip_runtime.h>
#include <hip/hip_bf16.h>

#define BS 64
#define SL 50
#define SW 64
#define DIM 128
#define VOC 100000
#define VT 6250              // vocab tiles of 16
#define K4_BLOCKS 1563       // ceil(6250/4)

typedef __attribute__((ext_vector_type(8))) short short8;
typedef __attribute__((ext_vector_type(4))) float float4v;

// f32 -> bf16 bits, round-to-nearest-even (pure integer ops)
__device__ __forceinline__ short f2b(float f){
    unsigned int u = __float_as_uint(f);
    u += 0x7fffu + ((u >> 16) & 1u);
    return (short)(u >> 16);
}

// ---- K1: per-sentence gathered sums -> m[h][b][s][d], c[h][b][s][d] (f32) ----
// float4 (16 B/lane) gathers: one wave instruction fetches TWO 512 B table rows
// (lanes 0-31 = word 2i, lanes 32-63 = word 2i+1). 32 VMEM ops/thread instead
// of 64; per-instruction footprint 1 KB. Cross-half combine happens in the
// existing LDS reduction (8 partial groups).
__global__ __launch_bounds__(256) void k_gather(const int* __restrict__ x,
    const float* __restrict__ A, const float* __restrict__ TA,
    const float* __restrict__ TC, float* __restrict__ m, float* __restrict__ c)
{
    int s = blockIdx.x, b = blockIdx.y;
    int tid = threadIdx.x;
    int wv = tid >> 6, l = tid & 63;
    int half = l >> 5, cl = l & 31;          // cl*4.. = my 4 dims
    const int* xp = x + (b * SL + s) * SW;
    int myidx = xp[l];                        // whole sentence in one load
    const float4v* A4 = (const float4v*)A;    // one row = 32 float4
    float aPE[3][4] = {{0.f,0.f,0.f,0.f},{0.f,0.f,0.f,0.f},{0.f,0.f,0.f,0.f}};
    float aPL[3][4] = {{0.f,0.f,0.f,0.f},{0.f,0.f,0.f,0.f},{0.f,0.f,0.f,0.f}};
    float kk[4];
    #pragma unroll
    for (int jj = 0; jj < 4; ++jj) kk[jj] = (cl * 4 + jj + 1) * (1.0f / DIM);
    #pragma unroll
    for (int wi = 0; wi < 8; ++wi) {
        int word = wv * 16 + wi * 2 + half;   // this half-wave's word
        int idx  = __shfl(myidx, word);
        float jw   = (word + 1) * (1.0f / SW);
        float om   = 1.0f - 2.0f * jw;
        float base = 1.0f - jw;
        float pe[4];
        #pragma unroll
        for (int jj = 0; jj < 4; ++jj) pe[jj] = base - kk[jj] * om;
        size_t roff = (size_t)idx * 32 + cl;
        #pragma unroll
        for (int t = 0; t < 4; ++t) {
            float4v v = A4[(size_t)t * (VOC * 32) + roff];
            if (t < 3) {
                #pragma unroll
                for (int jj = 0; jj < 4; ++jj) aPE[t][jj] += v[jj] * pe[jj];
            }
            if (t > 0) {
                #pragma unroll
                for (int jj = 0; jj < 4; ++jj) aPL[t-1][jj] += v[jj];
            }
        }
    }
    __shared__ float red[8][6][DIM];          // 24 KB
    int rr = wv * 2 + half;
    #pragma unroll
    for (int t = 0; t < 3; ++t) {
        #pragma unroll
        for (int jj = 0; jj < 4; ++jj) {
            red[rr][t  ][cl*4+jj] = aPE[t][jj];
            red[rr][3+t][cl*4+jj] = aPL[t][jj];
        }
    }
    __syncthreads();
    if (tid < DIM) {
        int d = tid;
        float ta = TA[s * DIM + d];
        float tc = TC[s * DIM + d];
        #pragma unroll
        for (int t = 0; t < 3; ++t) {
            float spe = 0.f, spl = 0.f;
            #pragma unroll
            for (int g = 0; g < 8; ++g) { spe += red[g][t][d]; spl += red[g][3+t][d]; }
            size_t o = (((size_t)t * BS + b) * SL + s) * DIM + d;
            m[o] = spe + ta;
            c[o] = spl + tc;
        }
    }
}

// ---- K2: u = A[0][q].sum ; 3x (p=softmax(m.u), u+=p.c) ; emit u16 bf16 bits ----
// 4 waves per block: sentences strided across waves for both the m.u dots and
// the p.c accumulation; per-hop wave-partial du reduced through LDS. The 50-
// element softmax scans are redundant per thread (LDS broadcast reads, free).
__global__ __launch_bounds__(256) void k_hops(const int* __restrict__ q,
    const float* __restrict__ A, const float* __restrict__ m,
    const float* __restrict__ c, short* __restrict__ u16)
{
    int b = blockIdx.x, tid = threadIdx.x;
    int wv = tid >> 6, l = tid & 63;
    const float2* A2 = (const float2*)A;
    __shared__ float sc[SL];
    __shared__ float pu[4][DIM];
    // u init: wave wv sums its 4 query rows; reduce across waves via LDS
    float u0 = 0.f, u1 = 0.f;
    #pragma unroll
    for (int t = 0; t < 4; ++t) {
        int idx = q[b * 16 + wv * 4 + t];
        float2 v = A2[(size_t)idx * 64 + l];
        u0 += v.x; u1 += v.y;
    }
    pu[wv][2*l] = u0; pu[wv][2*l+1] = u1;
    __syncthreads();
    u0 = pu[0][2*l] + pu[1][2*l] + pu[2][2*l] + pu[3][2*l];
    u1 = pu[0][2*l+1] + pu[1][2*l+1] + pu[2][2*l+1] + pu[3][2*l+1];
    for (int h = 0; h < 3; ++h) {
        const float2* mb = (const float2*)(m + ((size_t)h * BS + b) * SL * DIM);
        const float2* cb = (const float2*)(c + ((size_t)h * BS + b) * SL * DIM);
        for (int s = wv; s < SL; s += 4) {
            float2 w = mb[s * 64 + l];
            float p = w.x * u0 + w.y * u1;
            #pragma unroll
            for (int off = 32; off; off >>= 1) p += __shfl_down(p, off);
            if (l == 0) sc[s] = p;
        }
        __syncthreads();                       // sc complete (also fences pu)
        float mx = -1e30f;
        for (int s = 0; s < SL; ++s) mx = fmaxf(mx, sc[s]);
        float sum = 0.f;
        for (int s = 0; s < SL; ++s) sum += __expf(sc[s] - mx);
        float inv = 1.0f / sum;
        float d0 = 0.f, d1 = 0.f;
        for (int s = wv; s < SL; s += 4) {
            float p = __expf(sc[s] - mx) * inv;
            float2 w = cb[s * 64 + l];
            d0 += p * w.x; d1 += p * w.y;
        }
        pu[wv][2*l] = d0; pu[wv][2*l+1] = d1;
        __syncthreads();                       // du partials complete
        u0 += pu[0][2*l] + pu[1][2*l] + pu[2][2*l] + pu[3][2*l];
        u1 += pu[0][2*l+1] + pu[1][2*l+1] + pu[2][2*l+1] + pu[3][2*l+1];
        __syncthreads();                       // protect sc/pu for next hop
    }
    if (wv == 0) {
        u16[b * DIM + 2*l]     = f2b(u0);
        u16[b * DIM + 2*l + 1] = f2b(u1);
    }
}

// ---- K3: logits = u @ A3^T via bf16 MFMA; f32 out; per-block expsum partials ----
__global__ __launch_bounds__(256) void k_logits(const float* __restrict__ A3,
    const short* __restrict__ u16g, float* __restrict__ out, float* __restrict__ part)
{
    __shared__ short su[BS * DIM];     // 16 KB staged A-operand
    __shared__ float lpart[4][64];
    int tid = threadIdx.x;
    const int* ug = (const int*)u16g;
    int* us = (int*)su;
    #pragma unroll
    for (int i = 0; i < 16; ++i) us[tid + 256 * i] = ug[tid + 256 * i];
    int wv = tid >> 6, lane = tid & 63;
    lpart[wv][lane] = 0.0f;
    __syncthreads();
    int n = lane & 15, qd = lane >> 4;
    int tile = blockIdx.x * 4 + wv;
    if (tile < VT) {
        short8 bfr[4];
        size_t brow = ((size_t)(tile * 16 + n)) * DIM + qd * 8;
        #pragma unroll
        for (int k = 0; k < 4; ++k) {
            const float* p = A3 + brow + (size_t)k * 32;
            float4v f0 = *(const float4v*)p;
            float4v f1 = *(const float4v*)(p + 4);
            bfr[k] = (short8){ f2b(f0.x), f2b(f0.y), f2b(f0.z), f2b(f0.w),
                               f2b(f1.x), f2b(f1.y), f2b(f1.z), f2b(f1.w) };
        }
        float4v acc[4];
        #pragma unroll
        for (int bt = 0; bt < 4; ++bt) {
            acc[bt] = (float4v){0.f, 0.f, 0.f, 0.f};
            int arow = (bt * 16 + n) * DIM + qd * 8;
            #pragma unroll
            for (int k = 0; k < 4; ++k) {
                short8 af = *(const short8*)(su + arow + k * 32);
                acc[bt] = __builtin_amdgcn_mfma_f32_16x16x32_bf16(af, bfr[k], acc[bt], 0, 0, 0);
            }
        }
        int v = tile * 16 + n;
        #pragma unroll
        for (int bt = 0; bt < 4; ++bt) {
            #pragma unroll
            for (int r = 0; r < 4; ++r) {
                int b = bt * 16 + qd * 4 + r;   // C/D: col=lane&15 (vocab), row=quad*4+reg (batch)
                float val = acc[bt][r];
                out[(size_t)b * VOC + v] = val;
                float e = __expf(val);
                e += __shfl_xor(e, 1);          // reduce across n within qd-group
                e += __shfl_xor(e, 2);
                e += __shfl_xor(e, 4);
                e += __shfl_xor(e, 8);
                if (n == 0) lpart[wv][b] = e;
            }
        }
    }
    __syncthreads();
    if (tid < 64)
        part[(size_t)blockIdx.x * 64 + tid] =
            lpart[0][tid] + lpart[1][tid] + lpart[2][tid] + lpart[3][tid];
}

// ---- K4: lse[b] = log(sum_blocks part) ----
__global__ void k_lse(const float* __restrict__ part, float* __restrict__ lse)
{
    int b = blockIdx.x, tid = threadIdx.x;   // 256 threads
    float s = 0.f;
    for (int i = tid; i < K4_BLOCKS; i += 256) s += part[(size_t)i * 64 + b];
    __shared__ float red[256];
    red[tid] = s;
    __syncthreads();
    for (int off = 128; off; off >>= 1) {
        if (tid < off) red[tid] += red[tid + off];
        __syncthreads();
    }
    if (tid == 0) lse[b] = logf(red[0]);
}

// ---- K5: out[b][v] -= lse[b] ----
__global__ void k_sub(float* __restrict__ out, const float* __restrict__ lse)
{
    int b = blockIdx.y;
    int i = blockIdx.x * 256 + threadIdx.x;   // float4 index
    float l = lse[b];
    if (i < VOC / 4) {
        float4v* p = (float4v*)(out + (size_t)b * VOC) + i;
        float4v t = *p;
        t.x -= l; t.y -= l; t.z -= l; t.w -= l;
        *p = t;
    }
}

extern "C" void kernel_launch(void* const* d_in, const int* in_sizes, int n_in,
                              void* d_out, int out_size, void* d_ws, size_t ws_size,
                              hipStream_t stream)
{
    const int*   x  = (const int*)d_in[0];
    const int*   q  = (const int*)d_in[1];
    const float* A  = (const float*)d_in[2];
    const float* TA = (const float*)d_in[3];
    const float* TC = (const float*)d_in[4];
    float* out = (float*)d_out;

    // ws use < 420 KB. Big m/c scratch lives inside d_out (6.4M f32 elems):
    // 2*1,228,800 f32 at out+0; dead before k_logits overwrites all of d_out.
    char*  ws   = (char*)d_ws;
    short* u16  = (short*)ws;              // 64*128*2 = 16384 B
    float* part = (float*)(ws + 16384);    // 1563*64*4 = 400128 B
    float* lse  = (float*)(ws + 16384 + 400128);   // 256 B

    float* m = out;
    float* c = m + (size_t)3 * BS * SL * DIM;   // end = 2,457,600 < 6,400,000

    k_gather<<<dim3(SL, BS), 256, 0, stream>>>(x, A, TA, TC, m, c);
    k_hops<<<BS, 256, 0, stream>>>(q, A, m, c, u16);
    k_logits<<<K4_BLOCKS, 256, 0, stream>>>(A + (size_t)3 * VOC * DIM, u16, out, part);
    k_lse<<<BS, 256, 0, stream>>>(part, lse);
    k_sub<<<dim3((VOC / 4 + 255) / 256, BS), 256, 0, stream>>>(out, lse);
}

// Round 2
// 354.695 us; speedup vs baseline: 1.1532x; 1.0289x over previous
//
#include <hip/hip_runtime.h>
#include <hip/hip_bf16.h>

#define BS 64
#define SL 50
#define SW 64
#define DIM 128
#define VOC 100000
#define VT 6250              // vocab tiles of 16
#define K4_BLOCKS 1563       // ceil(6250/4)

typedef __attribute__((ext_vector_type(8))) short short8;
typedef __attribute__((ext_vector_type(4))) float float4v;

// f32 -> bf16 bits, round-to-nearest-even (pure integer ops)
__device__ __forceinline__ short f2b(float f){
    unsigned int u = __float_as_uint(f);
    u += 0x7fffu + ((u >> 16) & 1u);
    return (short)(u >> 16);
}

// ---- K1: per-sentence gathered sums -> m[h][b][s][d], c[h][b][s][d] (f32) ----
// float4 (16 B/lane) gathers: one wave instruction fetches TWO 512 B table rows
// (lanes 0-31 = word 2i, lanes 32-63 = word 2i+1). Near the random-row gather
// ceiling (~4 TB/s effective on 419 MB) — left unchanged this round.
__global__ __launch_bounds__(256) void k_gather(const int* __restrict__ x,
    const float* __restrict__ A, const float* __restrict__ TA,
    const float* __restrict__ TC, float* __restrict__ m, float* __restrict__ c)
{
    int s = blockIdx.x, b = blockIdx.y;
    int tid = threadIdx.x;
    int wv = tid >> 6, l = tid & 63;
    int half = l >> 5, cl = l & 31;          // cl*4.. = my 4 dims
    const int* xp = x + (b * SL + s) * SW;
    int myidx = xp[l];                        // whole sentence in one load
    const float4v* A4 = (const float4v*)A;    // one row = 32 float4
    float aPE[3][4] = {{0.f,0.f,0.f,0.f},{0.f,0.f,0.f,0.f},{0.f,0.f,0.f,0.f}};
    float aPL[3][4] = {{0.f,0.f,0.f,0.f},{0.f,0.f,0.f,0.f},{0.f,0.f,0.f,0.f}};
    float kk[4];
    #pragma unroll
    for (int jj = 0; jj < 4; ++jj) kk[jj] = (cl * 4 + jj + 1) * (1.0f / DIM);
    #pragma unroll
    for (int wi = 0; wi < 8; ++wi) {
        int word = wv * 16 + wi * 2 + half;   // this half-wave's word
        int idx  = __shfl(myidx, word);
        float jw   = (word + 1) * (1.0f / SW);
        float om   = 1.0f - 2.0f * jw;
        float base = 1.0f - jw;
        float pe[4];
        #pragma unroll
        for (int jj = 0; jj < 4; ++jj) pe[jj] = base - kk[jj] * om;
        size_t roff = (size_t)idx * 32 + cl;
        #pragma unroll
        for (int t = 0; t < 4; ++t) {
            float4v v = A4[(size_t)t * (VOC * 32) + roff];
            if (t < 3) {
                #pragma unroll
                for (int jj = 0; jj < 4; ++jj) aPE[t][jj] += v[jj] * pe[jj];
            }
            if (t > 0) {
                #pragma unroll
                for (int jj = 0; jj < 4; ++jj) aPL[t-1][jj] += v[jj];
            }
        }
    }
    __shared__ float red[8][6][DIM];          // 24 KB
    int rr = wv * 2 + half;
    #pragma unroll
    for (int t = 0; t < 3; ++t) {
        #pragma unroll
        for (int jj = 0; jj < 4; ++jj) {
            red[rr][t  ][cl*4+jj] = aPE[t][jj];
            red[rr][3+t][cl*4+jj] = aPL[t][jj];
        }
    }
    __syncthreads();
    if (tid < DIM) {
        int d = tid;
        float ta = TA[s * DIM + d];
        float tc = TC[s * DIM + d];
        #pragma unroll
        for (int t = 0; t < 3; ++t) {
            float spe = 0.f, spl = 0.f;
            #pragma unroll
            for (int g = 0; g < 8; ++g) { spe += red[g][t][d]; spl += red[g][3+t][d]; }
            size_t o = (((size_t)t * BS + b) * SL + s) * DIM + d;
            m[o] = spe + ta;
            c[o] = spl + tc;
        }
    }
}

// ---- K2: u = A[0][q].sum ; 3x (p=softmax(m.u), u+=p.c) ; emit u16 bf16 bits ----
// 8 waves per block: sentences strided across waves for both the m.u dots and
// the p.c accumulation; per-hop wave-partial du reduced through LDS. The 50-
// element softmax scans are redundant per thread (LDS broadcast reads, free).
__global__ __launch_bounds__(512) void k_hops(const int* __restrict__ q,
    const float* __restrict__ A, const float* __restrict__ m,
    const float* __restrict__ c, short* __restrict__ u16)
{
    int b = blockIdx.x, tid = threadIdx.x;
    int wv = tid >> 6, l = tid & 63;
    const float2* A2 = (const float2*)A;
    __shared__ float sc[SL];
    __shared__ float pu[8][DIM];
    // u init: wave wv sums its 2 query rows; reduce across waves via LDS
    float u0 = 0.f, u1 = 0.f;
    #pragma unroll
    for (int t = 0; t < 2; ++t) {
        int idx = q[b * 16 + wv * 2 + t];
        float2 v = A2[(size_t)idx * 64 + l];
        u0 += v.x; u1 += v.y;
    }
    pu[wv][2*l] = u0; pu[wv][2*l+1] = u1;
    __syncthreads();
    u0 = 0.f; u1 = 0.f;
    #pragma unroll
    for (int g = 0; g < 8; ++g) { u0 += pu[g][2*l]; u1 += pu[g][2*l+1]; }
    for (int h = 0; h < 3; ++h) {
        const float2* mb = (const float2*)(m + ((size_t)h * BS + b) * SL * DIM);
        const float2* cb = (const float2*)(c + ((size_t)h * BS + b) * SL * DIM);
        for (int s = wv; s < SL; s += 8) {
            float2 w = mb[s * 64 + l];
            float p = w.x * u0 + w.y * u1;
            #pragma unroll
            for (int off = 32; off; off >>= 1) p += __shfl_down(p, off);
            if (l == 0) sc[s] = p;
        }
        __syncthreads();                       // sc complete (also fences pu)
        float mx = -1e30f;
        for (int s = 0; s < SL; ++s) mx = fmaxf(mx, sc[s]);
        float sum = 0.f;
        for (int s = 0; s < SL; ++s) sum += __expf(sc[s] - mx);
        float inv = 1.0f / sum;
        float d0 = 0.f, d1 = 0.f;
        for (int s = wv; s < SL; s += 8) {
            float p = __expf(sc[s] - mx) * inv;
            float2 w = cb[s * 64 + l];
            d0 += p * w.x; d1 += p * w.y;
        }
        pu[wv][2*l] = d0; pu[wv][2*l+1] = d1;
        __syncthreads();                       // du partials complete
        #pragma unroll
        for (int g = 0; g < 8; ++g) { u0 += pu[g][2*l]; u1 += pu[g][2*l+1]; }
        __syncthreads();                       // protect sc/pu for next hop
    }
    if (wv == 0) {
        u16[b * DIM + 2*l]     = f2b(u0);
        u16[b * DIM + 2*l + 1] = f2b(u1);
    }
}

// ---- K3: logits = u @ A3^T via bf16 MFMA; f32 out; per-block expsum partials ----
// su is XOR-swizzled (T2, byte ^= (row&7)<<4): the fragment read pattern
// (16 n-lanes at row stride 256 B, same column) was a 16-way bank conflict on
// ds_read_b128; after the swizzle the 16 rows cover all 8 bank-quads 2-way
// (free). Write side is row-aligned (64 lanes = exactly one 256 B row), so the
// same XOR is a within-row permutation — still conflict-free.
__global__ __launch_bounds__(256) void k_logits(const float* __restrict__ A3,
    const short* __restrict__ u16g, float* __restrict__ out, float* __restrict__ part)
{
    __shared__ short su[BS * DIM];     // 16 KB staged A-operand (swizzled)
    __shared__ float lpart[4][64];
    int tid = threadIdx.x;
    const int* ug = (const int*)u16g;
    char* sub = (char*)su;
    #pragma unroll
    for (int i = 0; i < 16; ++i) {
        int w  = (tid + 256 * i) * 4;                 // linear byte offset
        int sw = w ^ (((w >> 8) & 7) << 4);           // T2 swizzle
        *(int*)(sub + sw) = ug[tid + 256 * i];
    }
    int wv = tid >> 6, lane = tid & 63;
    lpart[wv][lane] = 0.0f;
    __syncthreads();
    int n = lane & 15, qd = lane >> 4;
    int tile = blockIdx.x * 4 + wv;
    if (tile < VT) {
        short8 bfr[4];
        size_t brow = ((size_t)(tile * 16 + n)) * DIM + qd * 8;
        #pragma unroll
        for (int k = 0; k < 4; ++k) {
            const float* p = A3 + brow + (size_t)k * 32;
            float4v f0 = *(const float4v*)p;
            float4v f1 = *(const float4v*)(p + 4);
            bfr[k] = (short8){ f2b(f0.x), f2b(f0.y), f2b(f0.z), f2b(f0.w),
                               f2b(f1.x), f2b(f1.y), f2b(f1.z), f2b(f1.w) };
        }
        float4v acc[4];
        #pragma unroll
        for (int bt = 0; bt < 4; ++bt) {
            acc[bt] = (float4v){0.f, 0.f, 0.f, 0.f};
            int rowb = bt * 16 + n;
            int rbase = rowb * 256 + qd * 16;         // byte offset in su
            int rx = (rowb & 7) << 4;
            #pragma unroll
            for (int k = 0; k < 4; ++k) {
                short8 af = *(const short8*)(sub + ((rbase + k * 64) ^ rx));
                acc[bt] = __builtin_amdgcn_mfma_f32_16x16x32_bf16(af, bfr[k], acc[bt], 0, 0, 0);
            }
        }
        int v = tile * 16 + n;
        #pragma unroll
        for (int bt = 0; bt < 4; ++bt) {
            #pragma unroll
            for (int r = 0; r < 4; ++r) {
                int b = bt * 16 + qd * 4 + r;   // C/D: col=lane&15 (vocab), row=quad*4+reg (batch)
                float val = acc[bt][r];
                out[(size_t)b * VOC + v] = val;
                float e = __expf(val);
                e += __shfl_xor(e, 1);          // reduce across n within qd-group
                e += __shfl_xor(e, 2);
                e += __shfl_xor(e, 4);
                e += __shfl_xor(e, 8);
                if (n == 0) lpart[wv][b] = e;
            }
        }
    }
    __syncthreads();
    if (tid < 64)
        part[(size_t)blockIdx.x * 64 + tid] =
            lpart[0][tid] + lpart[1][tid] + lpart[2][tid] + lpart[3][tid];
}

// ---- K4: lse[b] = log(sum_blocks part) ----
__global__ void k_lse(const float* __restrict__ part, float* __restrict__ lse)
{
    int b = blockIdx.x, tid = threadIdx.x;   // 256 threads
    float s = 0.f;
    for (int i = tid; i < K4_BLOCKS; i += 256) s += part[(size_t)i * 64 + b];
    __shared__ float red[256];
    red[tid] = s;
    __syncthreads();
    for (int off = 128; off; off >>= 1) {
        if (tid < off) red[tid] += red[tid + off];
        __syncthreads();
    }
    if (tid == 0) lse[b] = logf(red[0]);
}

// ---- K5: out[b][v] -= lse[b] ----
__global__ void k_sub(float* __restrict__ out, const float* __restrict__ lse)
{
    int b = blockIdx.y;
    int i = blockIdx.x * 256 + threadIdx.x;   // float4 index
    float l = lse[b];
    if (i < VOC / 4) {
        float4v* p = (float4v*)(out + (size_t)b * VOC) + i;
        float4v t = *p;
        t.x -= l; t.y -= l; t.z -= l; t.w -= l;
        *p = t;
    }
}

extern "C" void kernel_launch(void* const* d_in, const int* in_sizes, int n_in,
                              void* d_out, int out_size, void* d_ws, size_t ws_size,
                              hipStream_t stream)
{
    const int*   x  = (const int*)d_in[0];
    const int*   q  = (const int*)d_in[1];
    const float* A  = (const float*)d_in[2];
    const float* TA = (const float*)d_in[3];
    const float* TC = (const float*)d_in[4];
    float* out = (float*)d_out;

    // ws use < 420 KB. Big m/c scratch lives inside d_out (6.4M f32 elems):
    // 2*1,228,800 f32 at out+0; dead before k_logits overwrites all of d_out.
    char*  ws   = (char*)d_ws;
    short* u16  = (short*)ws;              // 64*128*2 = 16384 B
    float* part = (float*)(ws + 16384);    // 1563*64*4 = 400128 B
    float* lse  = (float*)(ws + 16384 + 400128);   // 256 B

    float* m = out;
    float* c = m + (size_t)3 * BS * SL * DIM;   // end = 2,457,600 < 6,400,000

    k_gather<<<dim3(SL, BS), 256, 0, stream>>>(x, A, TA, TC, m, c);
    k_hops<<<BS, 512, 0, stream>>>(q, A, m, c, u16);
    k_logits<<<K4_BLOCKS, 256, 0, stream>>>(A + (size_t)3 * VOC * DIM, u16, out, part);
    k_lse<<<BS, 256, 0, stream>>>(part, lse);
    k_sub<<<dim3((VOC / 4 + 255) / 256, BS), 256, 0, stream>>>(out, lse);
}